// Round 11
// baseline (228.112 us; speedup 1.0000x reference)
//
#include <hip/hip_runtime.h>

typedef __bf16 bf16x8 __attribute__((ext_vector_type(8)));
typedef __bf16 bf16x4 __attribute__((ext_vector_type(4)));
typedef float f32x4 __attribute__((ext_vector_type(4)));

#define DEVI __device__ __forceinline__

constexpr int NE = 1024;   // n_embd
constexpr int NH = 16;     // heads
constexpr int HD = 64;     // head dim
constexpr int BB = 2;      // batch
constexpr int TT = 2048;   // seq len
constexpr int MM = BB * TT;

DEVI unsigned short f2bf(float f) {
  union { float f; unsigned u; } v; v.f = f;
  unsigned r = v.u + 0x7FFFu + ((v.u >> 16) & 1u);  // RNE to bf16
  return (unsigned short)(r >> 16);
}

__global__ __launch_bounds__(256) void cvt_bf16(const float* __restrict__ in,
                                                unsigned short* __restrict__ out, int n4) {
  int i = blockIdx.x * blockDim.x + threadIdx.x;
  if (i >= n4) return;
  float4 v = reinterpret_cast<const float4*>(in)[i];
  ushort4 o;
  o.x = f2bf(v.x); o.y = f2bf(v.y); o.z = f2bf(v.z); o.w = f2bf(v.w);
  reinterpret_cast<ushort4*>(out)[i] = o;
}

// all 4 weight matrices -> one contiguous bf16 region (Wq,Wk,Wv,Wp), 2^20 float4s
__global__ __launch_bounds__(256) void cvt_w(const float* __restrict__ q, const float* __restrict__ k,
                                             const float* __restrict__ v, const float* __restrict__ p,
                                             unsigned short* __restrict__ out) {
  int i = blockIdx.x * blockDim.x + threadIdx.x;  // < 2^20
  const int seg = i >> 18;                        // NE*NE/4 = 2^18 per matrix
  const float* src = (seg == 0) ? q : (seg == 1) ? k : (seg == 2) ? v : p;
  float4 vv = reinterpret_cast<const float4*>(src)[i & 0x3FFFF];
  ushort4 o;
  o.x = f2bf(vv.x); o.y = f2bf(vv.y); o.z = f2bf(vv.z); o.w = f2bf(vv.w);
  reinterpret_cast<ushort4*>(out)[i] = o;
}

// C[M,N] = A[M,K] @ B[N,K]^T + bias.  Tile BM x 128, BK=32, 4 waves.
// Triple-buffered LDS, stage 2 K-tiles ahead, counted vmcnt (never 0 in main
// loop), raw s_barrier (no vmcnt(0) drain). 16B-slot XOR swizzle on BOTH sides.
// MODE 0 (BM=64): fp32 out row-major [M][NE].  MODE 1 (BM=128): fused QKV.
template <int BM, int MODE>
__global__ __launch_bounds__(256, (BM == 128) ? 3 : 2)
void gemm_nt(const unsigned short* __restrict__ A, const unsigned short* __restrict__ Bm,
             const float* __restrict__ b0, const float* __restrict__ b1, const float* __restrict__ b2,
             void* __restrict__ o0, unsigned short* __restrict__ o1, unsigned short* __restrict__ o2,
             int K, int nbx) {
  constexpr int WAVES_N = (BM == 128) ? 2 : 4;
  constexpr int NJ = (BM == 128) ? 4 : 2;   // N fragments per wave
  constexpr int A_LPW = BM / 64;            // A chunks per wave per tile
  __shared__ __align__(16) unsigned short As[3][BM * 32];
  __shared__ __align__(16) unsigned short Bs[3][128 * 32];
  const int tid = threadIdx.x;
  const int wid = tid >> 6;
  const int lane = tid & 63;
  const int l15 = lane & 15, l4 = lane >> 4;

  // bijective XCD swizzle over linear grid (gridDim.x % 8 == 0)
  const int id = blockIdx.x;
  const int chunk = gridDim.x >> 3;
  const int idp = (id & 7) * chunk + (id >> 3);
  const int bx = idp / (gridDim.x / nbx), by = idp % (gridDim.x / nbx);

  const int brow = by * BM;
  const int bcol = bx * 128;
  const int wm = wid / WAVES_N, wn = wid % WAVES_N;
  const int wmoff = wm * 64;
  const int wnoff = wn * (128 / WAVES_N);

  f32x4 acc[4][NJ] = {};

  const int srow = lane >> 2;
  const int sscol = ((lane & 3) ^ ((lane >> 3) & 3)) * 8;

  auto stage = [&](int buf, int t) {
    const int kb = t * 32;
#pragma unroll
    for (int c = 0; c < A_LPW; ++c) {
      const int rb = wid * (BM / 4) + c * 16;
      __builtin_amdgcn_global_load_lds(
          (const __attribute__((address_space(1))) void*)(A + (size_t)(brow + rb + srow) * K + kb + sscol),
          (__attribute__((address_space(3))) void*)&As[buf][rb * 32], 16, 0, 0);
    }
#pragma unroll
    for (int c = 0; c < 2; ++c) {
      const int rb = wid * 32 + c * 16;
      __builtin_amdgcn_global_load_lds(
          (const __attribute__((address_space(1))) void*)(Bm + (size_t)(bcol + rb + srow) * K + kb + sscol),
          (__attribute__((address_space(3))) void*)&Bs[buf][rb * 32], 16, 0, 0);
    }
  };

  const int roff = l15 * 32 + (l4 ^ ((l15 >> 1) & 3)) * 8;

  auto compute = [&](int cb) {
    bf16x8 af[4], bfj[NJ];
#pragma unroll
    for (int i = 0; i < 4; ++i)
      af[i] = *reinterpret_cast<const bf16x8*>(&As[cb][(wmoff + i * 16) * 32 + roff]);
#pragma unroll
    for (int j = 0; j < NJ; ++j)
      bfj[j] = *reinterpret_cast<const bf16x8*>(&Bs[cb][(wnoff + j * 16) * 32 + roff]);
#pragma unroll
    for (int i = 0; i < 4; ++i)
#pragma unroll
      for (int j = 0; j < NJ; ++j)
        acc[i][j] = __builtin_amdgcn_mfma_f32_16x16x32_bf16(af[i], bfj[j], acc[i][j], 0, 0, 0);
  };

  const int NT = K / 32;  // >= 2
  stage(0, 0);
  stage(1, 1);
  int cb = 0, sb = 2;
  for (int t = 0; t + 2 < NT; ++t) {
    stage(sb, t + 2);
    if constexpr (BM == 128) asm volatile("s_waitcnt vmcnt(8)" ::: "memory");
    else                     asm volatile("s_waitcnt vmcnt(6)" ::: "memory");
    asm volatile("s_barrier" ::: "memory");
    compute(cb);
    asm volatile("s_barrier" ::: "memory");
    sb = cb;
    cb = (cb == 2) ? 0 : cb + 1;
  }
  if constexpr (BM == 128) asm volatile("s_waitcnt vmcnt(4)" ::: "memory");
  else                     asm volatile("s_waitcnt vmcnt(3)" ::: "memory");
  asm volatile("s_barrier" ::: "memory");
  compute(cb);
  asm volatile("s_barrier" ::: "memory");
  cb = (cb == 2) ? 0 : cb + 1;
  asm volatile("s_waitcnt vmcnt(0)" ::: "memory");
  asm volatile("s_barrier" ::: "memory");
  compute(cb);

  if (MODE == 0) {
#pragma unroll
    for (int j = 0; j < NJ; ++j) {
      const int col = bcol + wnoff + j * 16 + l15;
      const float bv = b0[col];
#pragma unroll
      for (int i = 0; i < 4; ++i) {
        const int row0 = brow + wmoff + i * 16 + l4 * 4;
#pragma unroll
        for (int r = 0; r < 4; ++r)
          ((float*)o0)[(size_t)(row0 + r) * NE + col] = acc[i][j][r] + bv;
      }
    }
  } else {
    const int seg = bcol >> 10;  // block-uniform (128 | 1024)
    const float* bsel = (seg == 0) ? b0 : (seg == 1) ? b1 : b2;
    unsigned short* qk = (seg == 0) ? (unsigned short*)o0 : o1;
#pragma unroll
    for (int j = 0; j < NJ; ++j) {
      const int col = bcol + wnoff + j * 16 + l15;
      const int dcol = col & 1023;
      const int h = dcol >> 6, d = dcol & 63;
      const float bv = bsel[dcol];
#pragma unroll
      for (int i = 0; i < 4; ++i) {
        const int row0 = brow + wmoff + i * 16 + l4 * 4;
#pragma unroll
        for (int r = 0; r < 4; ++r) {
          const int row = row0 + r;
          const int b = row >> 11, t = row & (TT - 1);
          const unsigned short val = f2bf(acc[i][j][r] + bv);
          if (seg < 2)
            qk[((size_t)((b * NH + h) * TT + t) << 6) + d] = val;
          else
            o2[((size_t)(b * NH + h) * HD + d) * TT + t] = val;
        }
      }
    }
  }
}

// Flash attention, EQUAL-WORK blocks: 8 waves x 32 q-rows; waves 0-3 own
// q-tile p, waves 4-7 own q-tile 15-p -> every block = 34 wave-tile units,
// 256 blocks = 1/CU -> deterministic balance independent of the scheduler's
// block->CU mapping. K/Vt tiles staged once per block serve both q-tiles.
// Same-bh blocks land on one XCD (id%8 = bh%8) -> K/V L2 reuse.
// R8 dbuf+syncthreads schedule (measured faster than tbuf/counted-vmcnt).
// Swapped QK^T, exp2-domain softmax, diag-only masking, skip masked tiles,
// defer-max, setprio around MFMA clusters.
__global__ __launch_bounds__(512, 1)
void attn(const unsigned short* __restrict__ Q, const unsigned short* __restrict__ Kk,
          const unsigned short* __restrict__ Vt, unsigned short* __restrict__ Y) {
  __shared__ __align__(16) unsigned short Ks[2][64 * 64];
  __shared__ __align__(16) unsigned short Vs[2][64 * 64];
  __shared__ __align__(16) unsigned short Pw[8][32 * 64];
  const int tid = threadIdx.x, wid = tid >> 6, lane = tid & 63;
  const int l15 = lane & 15, l4 = lane >> 4;

  const int id = blockIdx.x;               // [0, 256)
  const int bh = (id & 7) + 8 * (id >> 6); // fixed bh -> fixed id%8 -> one XCD
  const int p = (id >> 3) & 7;             // low q-tile index
  const int xtw = (wid < 4) ? p : (15 - p);
  const int qw = xtw * 128 + (wid & 3) * 32;
  const int nkb = 2 * (16 - p);            // key tiles needed by the high tile

  const unsigned short* Qh = Q + (size_t)bh * TT * HD;
  const unsigned short* Kh = Kk + (size_t)bh * TT * HD;
  const unsigned short* Vh = Vt + (size_t)bh * HD * TT;

  // Q fragments hoisted to registers, pre-scaled by 0.125*log2(e) (exp2 domain)
  bf16x8 qf[2][2];
#pragma unroll
  for (int qt = 0; qt < 2; ++qt)
#pragma unroll
    for (int ks = 0; ks < 2; ++ks) {
      bf16x8 t = *reinterpret_cast<const bf16x8*>(&Qh[(qw + qt * 16 + l15) * 64 + ks * 32 + l4 * 8]);
#pragma unroll
      for (int e = 0; e < 8; ++e) t[e] = (__bf16)((float)t[e] * 0.18033688011f);
      qf[qt][ks] = t;
    }

  float m_[2] = {-3e38f, -3e38f};
  float l_[2] = {0.f, 0.f};
  f32x4 accO[4][2] = {};  // O^T: [dt][qt], row d = dt*16+l4*4+r, col q = l15

  const int srow8 = lane >> 3;
  const int scol8 = lane & 7;

  auto stage = [&](int buf, int kb) {   // 2 loads per wave (8 waves cover 8+8 chunks)
    const int row = wid * 8 + srow8;
    const int sc = (scol8 ^ srow8) * 8;  // row&7 == srow8
    __builtin_amdgcn_global_load_lds(
        (const __attribute__((address_space(1))) void*)(Kh + (size_t)(kb + row) * 64 + sc),
        (__attribute__((address_space(3))) void*)&Ks[buf][wid * 512], 16, 0, 0);
    __builtin_amdgcn_global_load_lds(
        (const __attribute__((address_space(1))) void*)(Vh + (size_t)row * TT + kb + sc),
        (__attribute__((address_space(3))) void*)&Vs[buf][wid * 512], 16, 0, 0);
  };

  stage(0, 0);
  int cur = 0;
  for (int kbi = 0; kbi < nkb; ++kbi) {
    const int kb = kbi * 64;
    __syncthreads();                       // drains vmcnt -> buf[cur] ready
    if (kbi + 1 < nkb) stage(cur ^ 1, kb + 64);

    if (kb < qw + 32) {  // wave-uniform: this wave has unmasked keys in tile
      const bool diag = (kb + 63 > qw);
      const char* ksb = (const char*)Ks[cur];
      const char* vsb = (const char*)Vs[cur];
      char* pwb = (char*)&Pw[wid][0];

      f32x4 z[4][2];
      __builtin_amdgcn_s_setprio(1);
#pragma unroll
      for (int kt = 0; kt < 4; ++kt) {
        const int row = kt * 16 + l15;
        bf16x8 kf0 = *reinterpret_cast<const bf16x8*>(ksb + row * 128 + (((0 + l4) ^ (row & 7)) << 4));
        bf16x8 kf1 = *reinterpret_cast<const bf16x8*>(ksb + row * 128 + (((4 + l4) ^ (row & 7)) << 4));
#pragma unroll
        for (int qt = 0; qt < 2; ++qt) {
          f32x4 zz = {};
          zz = __builtin_amdgcn_mfma_f32_16x16x32_bf16(kf0, qf[qt][0], zz, 0, 0, 0);
          zz = __builtin_amdgcn_mfma_f32_16x16x32_bf16(kf1, qf[qt][1], zz, 0, 0, 0);
          z[kt][qt] = zz;
        }
      }
      __builtin_amdgcn_s_setprio(0);

      if (diag) {
#pragma unroll
        for (int kt = 0; kt < 4; ++kt)
#pragma unroll
          for (int qt = 0; qt < 2; ++qt)
#pragma unroll
            for (int r = 0; r < 4; ++r) {
              const int key = kb + kt * 16 + l4 * 4 + r;
              const int qi = qw + qt * 16 + l15;
              z[kt][qt][r] = (key <= qi) ? z[kt][qt][r] : -3e38f;
            }
      }

#pragma unroll
      for (int qt = 0; qt < 2; ++qt) {
        float tm[8];
#pragma unroll
        for (int i = 0; i < 8; ++i)
          tm[i] = fmaxf(z[(2 * i) >> 2][qt][(2 * i) & 3], z[(2 * i + 1) >> 2][qt][(2 * i + 1) & 3]);
#pragma unroll
        for (int i = 0; i < 4; ++i) tm[i] = fmaxf(tm[i], tm[i + 4]);
        float pm = fmaxf(fmaxf(tm[0], tm[2]), fmaxf(tm[1], tm[3]));
        pm = fmaxf(pm, __shfl_xor(pm, 16, 64));
        pm = fmaxf(pm, __shfl_xor(pm, 32, 64));

        if (!__all(pm <= m_[qt] + 11.5f)) {  // defer-max (log2 domain)
          const float mn = fmaxf(m_[qt], pm);
          const float sf = exp2f(m_[qt] - mn);
          m_[qt] = mn;
          l_[qt] *= sf;
#pragma unroll
          for (int dt = 0; dt < 4; ++dt)
#pragma unroll
            for (int r = 0; r < 4; ++r) accO[dt][qt][r] *= sf;
        }

#pragma unroll
        for (int kt = 0; kt < 4; ++kt)
#pragma unroll
          for (int r = 0; r < 4; ++r)
            z[kt][qt][r] = exp2f(z[kt][qt][r] - m_[qt]);
        float ts[8];
#pragma unroll
        for (int i = 0; i < 8; ++i)
          ts[i] = z[(2 * i) >> 2][qt][(2 * i) & 3] + z[(2 * i + 1) >> 2][qt][(2 * i + 1) & 3];
#pragma unroll
        for (int i = 0; i < 4; ++i) ts[i] += ts[i + 4];
        float rs = (ts[0] + ts[2]) + (ts[1] + ts[3]);
        rs += __shfl_xor(rs, 16, 64);
        rs += __shfl_xor(rs, 32, 64);
        l_[qt] += rs;

        const int q = qt * 16 + l15;
#pragma unroll
        for (int kt = 0; kt < 4; ++kt) {
          bf16x4 pk;
#pragma unroll
          for (int r = 0; r < 4; ++r) pk[r] = (__bf16)z[kt][qt][r];
          const int c16 = kt * 2 + (l4 >> 1);
          *reinterpret_cast<bf16x4*>(pwb + q * 128 + ((c16 ^ (q & 7)) << 4) + (l4 & 1) * 8) = pk;
        }
      }

      asm volatile("s_waitcnt lgkmcnt(0)" ::: "memory");
      __builtin_amdgcn_sched_barrier(0);

      __builtin_amdgcn_s_setprio(1);
#pragma unroll
      for (int ks = 0; ks < 2; ++ks) {
        bf16x8 pb[2];
#pragma unroll
        for (int qt = 0; qt < 2; ++qt) {
          const int q = qt * 16 + l15;
          pb[qt] = *reinterpret_cast<const bf16x8*>(pwb + q * 128 + ((((ks << 2) + l4) ^ (q & 7)) << 4));
        }
#pragma unroll
        for (int dt = 0; dt < 4; ++dt) {
          const int row = dt * 16 + l15;
          bf16x8 vf = *reinterpret_cast<const bf16x8*>(vsb + row * 128 + ((((ks << 2) + l4) ^ (row & 7)) << 4));
#pragma unroll
          for (int qt = 0; qt < 2; ++qt)
            accO[dt][qt] = __builtin_amdgcn_mfma_f32_16x16x32_bf16(vf, pb[qt], accO[dt][qt], 0, 0, 0);
        }
      }
      __builtin_amdgcn_s_setprio(0);
    }
    cur ^= 1;
  }

  const int b = bh >> 4, h = bh & 15;
#pragma unroll
  for (int qt = 0; qt < 2; ++qt) {
    const float inv = 1.0f / l_[qt];
    const int q = qw + qt * 16 + l15;
#pragma unroll
    for (int dt = 0; dt < 4; ++dt) {
      bf16x4 o;
#pragma unroll
      for (int r = 0; r < 4; ++r) o[r] = (__bf16)(accO[dt][qt][r] * inv);
      *reinterpret_cast<bf16x4*>(&Y[((size_t)(b * TT + q)) * NE + h * 64 + dt * 16 + l4 * 4]) = o;
    }
  }
}

extern "C" void kernel_launch(void* const* d_in, const int* in_sizes, int n_in,
                              void* d_out, int out_size, void* d_ws, size_t ws_size,
                              hipStream_t stream) {
  const float* x  = (const float*)d_in[0];
  const float* Wq = (const float*)d_in[1];
  const float* bq = (const float*)d_in[2];
  const float* Wk = (const float*)d_in[3];
  const float* bk = (const float*)d_in[4];
  const float* Wv = (const float*)d_in[5];
  const float* bv = (const float*)d_in[6];
  const float* Wp = (const float*)d_in[7];
  const float* bp = (const float*)d_in[8];

  char* ws = (char*)d_ws;
  const size_t MB = 1u << 20;
  unsigned short* xb   = (unsigned short*)(ws + 0 * MB);   // 8 MB  [4096][1024]
  unsigned short* Wqkv = (unsigned short*)(ws + 8 * MB);   // 6 MB  [3072][1024] (q,k,v)
  unsigned short* Wpb  = (unsigned short*)(ws + 14 * MB);  // 2 MB  [1024][1024]
  unsigned short* Qb   = (unsigned short*)(ws + 16 * MB);  // 8 MB  [B,H,T,64]
  unsigned short* Kb   = (unsigned short*)(ws + 24 * MB);  // 8 MB  [B,H,T,64]
  unsigned short* Vtb  = (unsigned short*)(ws + 32 * MB);  // 8 MB  [B,H,64,T]
  unsigned short* yb   = (unsigned short*)(ws + 40 * MB);  // 8 MB  [B,T,NE]

  cvt_bf16<<<MM * NE / 4 / 256, 256, 0, stream>>>(x, xb, MM * NE / 4);
  cvt_w<<<4 * NE * NE / 4 / 256, 256, 0, stream>>>(Wq, Wk, Wv, Wp, Wqkv);

  // fused QKV: M=4096, N=3072 -> 24 x 32 = 768 blocks (3/CU)
  gemm_nt<128, 1><<<768, 256, 0, stream>>>(xb, Wqkv, bq, bk, bv, Qb, Kb, Vtb, NE, 24);

  attn<<<256, 512, 0, stream>>>(Qb, Kb, Vtb, yb);

  // proj: BM=64 -> 8 x 64 = 512 blocks (2/CU)
  gemm_nt<64, 0><<<512, 256, 0, stream>>>(yb, Wpb, bp, nullptr, nullptr, d_out, nullptr, nullptr, NE, 8);
}

// Round 12
// 214.906 us; speedup vs baseline: 1.0614x; 1.0614x over previous
//
#include <hip/hip_runtime.h>

typedef __bf16 bf16x8 __attribute__((ext_vector_type(8)));
typedef __bf16 bf16x4 __attribute__((ext_vector_type(4)));
typedef float f32x4 __attribute__((ext_vector_type(4)));

#define DEVI __device__ __forceinline__

constexpr int NE = 1024;   // n_embd
constexpr int NH = 16;     // heads
constexpr int HD = 64;     // head dim
constexpr int BB = 2;      // batch
constexpr int TT = 2048;   // seq len
constexpr int MM = BB * TT;

DEVI unsigned short f2bf(float f) {
  union { float f; unsigned u; } v; v.f = f;
  unsigned r = v.u + 0x7FFFu + ((v.u >> 16) & 1u);  // RNE to bf16
  return (unsigned short)(r >> 16);
}

__global__ __launch_bounds__(256) void cvt_bf16(const float* __restrict__ in,
                                                unsigned short* __restrict__ out, int n4) {
  int i = blockIdx.x * blockDim.x + threadIdx.x;
  if (i >= n4) return;
  float4 v = reinterpret_cast<const float4*>(in)[i];
  ushort4 o;
  o.x = f2bf(v.x); o.y = f2bf(v.y); o.z = f2bf(v.z); o.w = f2bf(v.w);
  reinterpret_cast<ushort4*>(out)[i] = o;
}

// all 4 weight matrices -> one contiguous bf16 region (Wq,Wk,Wv,Wp), 2^20 float4s
__global__ __launch_bounds__(256) void cvt_w(const float* __restrict__ q, const float* __restrict__ k,
                                             const float* __restrict__ v, const float* __restrict__ p,
                                             unsigned short* __restrict__ out) {
  int i = blockIdx.x * blockDim.x + threadIdx.x;  // < 2^20
  const int seg = i >> 18;                        // NE*NE/4 = 2^18 per matrix
  const float* src = (seg == 0) ? q : (seg == 1) ? k : (seg == 2) ? v : p;
  float4 vv = reinterpret_cast<const float4*>(src)[i & 0x3FFFF];
  ushort4 o;
  o.x = f2bf(vv.x); o.y = f2bf(vv.y); o.z = f2bf(vv.z); o.w = f2bf(vv.w);
  reinterpret_cast<ushort4*>(out)[i] = o;
}

// C[M,N] = A[M,K] @ B[N,K]^T + bias.  Tile BM x 128, BK=32, 4 waves.
// Triple-buffered LDS, stage 2 K-tiles ahead, counted vmcnt (never 0 in main
// loop), raw s_barrier (no vmcnt(0) drain). 16B-slot XOR swizzle on BOTH sides.
// MODE 0 (BM=64): fp32 out row-major [M][NE].  MODE 1 (BM=128): fused QKV.
template <int BM, int MODE>
__global__ __launch_bounds__(256, (BM == 128) ? 3 : 2)
void gemm_nt(const unsigned short* __restrict__ A, const unsigned short* __restrict__ Bm,
             const float* __restrict__ b0, const float* __restrict__ b1, const float* __restrict__ b2,
             void* __restrict__ o0, unsigned short* __restrict__ o1, unsigned short* __restrict__ o2,
             int K, int nbx) {
  constexpr int WAVES_N = (BM == 128) ? 2 : 4;
  constexpr int NJ = (BM == 128) ? 4 : 2;   // N fragments per wave
  constexpr int A_LPW = BM / 64;            // A chunks per wave per tile
  __shared__ __align__(16) unsigned short As[3][BM * 32];
  __shared__ __align__(16) unsigned short Bs[3][128 * 32];
  const int tid = threadIdx.x;
  const int wid = tid >> 6;
  const int lane = tid & 63;
  const int l15 = lane & 15, l4 = lane >> 4;

  // bijective XCD swizzle over linear grid (gridDim.x % 8 == 0)
  const int id = blockIdx.x;
  const int chunk = gridDim.x >> 3;
  const int idp = (id & 7) * chunk + (id >> 3);
  const int bx = idp / (gridDim.x / nbx), by = idp % (gridDim.x / nbx);

  const int brow = by * BM;
  const int bcol = bx * 128;
  const int wm = wid / WAVES_N, wn = wid % WAVES_N;
  const int wmoff = wm * 64;
  const int wnoff = wn * (128 / WAVES_N);

  f32x4 acc[4][NJ] = {};

  const int srow = lane >> 2;
  const int sscol = ((lane & 3) ^ ((lane >> 3) & 3)) * 8;

  auto stage = [&](int buf, int t) {
    const int kb = t * 32;
#pragma unroll
    for (int c = 0; c < A_LPW; ++c) {
      const int rb = wid * (BM / 4) + c * 16;
      __builtin_amdgcn_global_load_lds(
          (const __attribute__((address_space(1))) void*)(A + (size_t)(brow + rb + srow) * K + kb + sscol),
          (__attribute__((address_space(3))) void*)&As[buf][rb * 32], 16, 0, 0);
    }
#pragma unroll
    for (int c = 0; c < 2; ++c) {
      const int rb = wid * 32 + c * 16;
      __builtin_amdgcn_global_load_lds(
          (const __attribute__((address_space(1))) void*)(Bm + (size_t)(bcol + rb + srow) * K + kb + sscol),
          (__attribute__((address_space(3))) void*)&Bs[buf][rb * 32], 16, 0, 0);
    }
  };

  const int roff = l15 * 32 + (l4 ^ ((l15 >> 1) & 3)) * 8;

  auto compute = [&](int cb) {
    bf16x8 af[4], bfj[NJ];
#pragma unroll
    for (int i = 0; i < 4; ++i)
      af[i] = *reinterpret_cast<const bf16x8*>(&As[cb][(wmoff + i * 16) * 32 + roff]);
#pragma unroll
    for (int j = 0; j < NJ; ++j)
      bfj[j] = *reinterpret_cast<const bf16x8*>(&Bs[cb][(wnoff + j * 16) * 32 + roff]);
#pragma unroll
    for (int i = 0; i < 4; ++i)
#pragma unroll
      for (int j = 0; j < NJ; ++j)
        acc[i][j] = __builtin_amdgcn_mfma_f32_16x16x32_bf16(af[i], bfj[j], acc[i][j], 0, 0, 0);
  };

  const int NT = K / 32;  // >= 2
  stage(0, 0);
  stage(1, 1);
  int cb = 0, sb = 2;
  for (int t = 0; t + 2 < NT; ++t) {
    stage(sb, t + 2);
    if constexpr (BM == 128) asm volatile("s_waitcnt vmcnt(8)" ::: "memory");
    else                     asm volatile("s_waitcnt vmcnt(6)" ::: "memory");
    asm volatile("s_barrier" ::: "memory");
    compute(cb);
    asm volatile("s_barrier" ::: "memory");
    sb = cb;
    cb = (cb == 2) ? 0 : cb + 1;
  }
  if constexpr (BM == 128) asm volatile("s_waitcnt vmcnt(4)" ::: "memory");
  else                     asm volatile("s_waitcnt vmcnt(3)" ::: "memory");
  asm volatile("s_barrier" ::: "memory");
  compute(cb);
  asm volatile("s_barrier" ::: "memory");
  cb = (cb == 2) ? 0 : cb + 1;
  asm volatile("s_waitcnt vmcnt(0)" ::: "memory");
  asm volatile("s_barrier" ::: "memory");
  compute(cb);

  if (MODE == 0) {
#pragma unroll
    for (int j = 0; j < NJ; ++j) {
      const int col = bcol + wnoff + j * 16 + l15;
      const float bv = b0[col];
#pragma unroll
      for (int i = 0; i < 4; ++i) {
        const int row0 = brow + wmoff + i * 16 + l4 * 4;
#pragma unroll
        for (int r = 0; r < 4; ++r)
          ((float*)o0)[(size_t)(row0 + r) * NE + col] = acc[i][j][r] + bv;
      }
    }
  } else {
    const int seg = bcol >> 10;  // block-uniform (128 | 1024)
    const float* bsel = (seg == 0) ? b0 : (seg == 1) ? b1 : b2;
    unsigned short* qk = (seg == 0) ? (unsigned short*)o0 : o1;
#pragma unroll
    for (int j = 0; j < NJ; ++j) {
      const int col = bcol + wnoff + j * 16 + l15;
      const int dcol = col & 1023;
      const int h = dcol >> 6, d = dcol & 63;
      const float bv = bsel[dcol];
#pragma unroll
      for (int i = 0; i < 4; ++i) {
        const int row0 = brow + wmoff + i * 16 + l4 * 4;
#pragma unroll
        for (int r = 0; r < 4; ++r) {
          const int row = row0 + r;
          const int b = row >> 11, t = row & (TT - 1);
          const unsigned short val = f2bf(acc[i][j][r] + bv);
          if (seg < 2)
            qk[((size_t)((b * NH + h) * TT + t) << 6) + d] = val;
          else
            o2[((size_t)(b * NH + h) * HD + d) * TT + t] = val;
        }
      }
    }
  }
}

// Flash attention, block = 4 waves x 32 q-rows = 128 q-rows of one (b,h).
// KVBLK = 128: half the iterations/barriers of R8; one softmax reduction,
// rescale and defer-max check per 128 keys. K staged [128][64] (8-slot XOR
// swizzle), Vt staged [64][128] (16-slot XOR swizzle). PV in two 64-key
// halves reusing one 4KB/wave P buffer (lgkmcnt fence per half, no barrier).
// LDS = 80 KB -> 2 blocks/CU (TLP, the R8->R11 lesson). R8 block mapping:
// same-bh blocks on one XCD -> K/V L2 reuse (FETCH ~12 MB). Swapped QK^T,
// exp2-domain softmax, only the last tile is diagonal (block-uniform).
__global__ __launch_bounds__(256, 2)
void attn(const unsigned short* __restrict__ Q, const unsigned short* __restrict__ Kk,
          const unsigned short* __restrict__ Vt, unsigned short* __restrict__ Y) {
  __shared__ __align__(16) unsigned short Ks[2][128 * 64];
  __shared__ __align__(16) unsigned short Vs[2][64 * 128];
  __shared__ __align__(16) unsigned short Pw[4][32 * 64];
  const int tid = threadIdx.x, wid = tid >> 6, lane = tid & 63;
  const int l15 = lane & 15, l4 = lane >> 4;

  // R8 mapping: ids with equal bh are ≡ (mod 16) -> same XCD (id%8).
  const int id = blockIdx.x;          // [0, 512)
  const int j = id & 255, kk = id >> 8;
  const int bh = (j & 15) + 16 * kk;
  const int xt = kk ? 15 - (j >> 4) : (j >> 4);

  const int qw = xt * 128 + wid * 32;
  const int nkb = xt + 1;             // 128-key tiles
  const unsigned short* Qh = Q + (size_t)bh * TT * HD;
  const unsigned short* Kh = Kk + (size_t)bh * TT * HD;
  const unsigned short* Vh = Vt + (size_t)bh * HD * TT;

  // Q fragments hoisted to registers, pre-scaled by 0.125*log2(e) (exp2 domain)
  bf16x8 qf[2][2];
#pragma unroll
  for (int qt = 0; qt < 2; ++qt)
#pragma unroll
    for (int ks = 0; ks < 2; ++ks) {
      bf16x8 t = *reinterpret_cast<const bf16x8*>(&Qh[(qw + qt * 16 + l15) * 64 + ks * 32 + l4 * 8]);
#pragma unroll
      for (int e = 0; e < 8; ++e) t[e] = (__bf16)((float)t[e] * 0.18033688011f);
      qf[qt][ks] = t;
    }

  float m_[2] = {-3e38f, -3e38f};
  float l_[2] = {0.f, 0.f};
  f32x4 accO[4][2] = {};  // O^T: [dt][qt], row d = dt*16+l4*4+r, col q = l15

  auto stage = [&](int buf, int kb) {   // 8 loads per wave
    // K tile: 128 rows x 64 cols; 4 chunks of 8 rows per wave
#pragma unroll
    for (int c = 0; c < 4; ++c) {
      const int row = wid * 32 + c * 8 + (lane >> 3);
      const int sc = ((lane & 7) ^ (lane >> 3)) * 8;   // row&7 == lane>>3
      __builtin_amdgcn_global_load_lds(
          (const __attribute__((address_space(1))) void*)(Kh + (size_t)(kb + row) * 64 + sc),
          (__attribute__((address_space(3))) void*)&Ks[buf][(wid * 32 + c * 8) * 64], 16, 0, 0);
    }
    // V tile: 64 rows x 128 cols; 4 chunks of 4 rows per wave
#pragma unroll
    for (int c = 0; c < 4; ++c) {
      const int row = wid * 16 + c * 4 + (lane >> 4);
      const int sc = ((lane & 15) ^ (c * 4 + (lane >> 4))) * 8;  // row&15
      __builtin_amdgcn_global_load_lds(
          (const __attribute__((address_space(1))) void*)(Vh + (size_t)row * TT + kb + sc),
          (__attribute__((address_space(3))) void*)&Vs[buf][(wid * 16 + c * 4) * 128], 16, 0, 0);
    }
  };

  stage(0, 0);
  int cur = 0;
  for (int kbi = 0; kbi < nkb; ++kbi) {
    const int kb = kbi * 128;
    __syncthreads();                       // drains vmcnt -> buf[cur] ready
    if (kbi + 1 < nkb) stage(cur ^ 1, kb + 128);

    const bool diag = (kbi == nkb - 1);    // only last tile crosses the diagonal
    const char* ksb = (const char*)Ks[cur];
    const char* vsb = (const char*)Vs[cur];
    char* pwb = (char*)&Pw[wid][0];

    // QK^T swapped: z[kt][qt], lane holds S^T[key=kb+kt*16+l4*4+r][q=qw+qt*16+l15]
    f32x4 z[8][2];
    __builtin_amdgcn_s_setprio(1);
#pragma unroll
    for (int kt = 0; kt < 8; ++kt) {
      const int row = kt * 16 + l15;
      const char* base = ksb + row * 128;
      bf16x8 kf0 = *reinterpret_cast<const bf16x8*>(base + (((0 + l4) ^ (l15 & 7)) << 4));
      bf16x8 kf1 = *reinterpret_cast<const bf16x8*>(base + (((4 + l4) ^ (l15 & 7)) << 4));
#pragma unroll
      for (int qt = 0; qt < 2; ++qt) {
        f32x4 zz = {};
        zz = __builtin_amdgcn_mfma_f32_16x16x32_bf16(kf0, qf[qt][0], zz, 0, 0, 0);
        zz = __builtin_amdgcn_mfma_f32_16x16x32_bf16(kf1, qf[qt][1], zz, 0, 0, 0);
        z[kt][qt] = zz;
      }
    }
    __builtin_amdgcn_s_setprio(0);

    if (diag) {
#pragma unroll
      for (int kt = 0; kt < 8; ++kt)
#pragma unroll
        for (int qt = 0; qt < 2; ++qt)
#pragma unroll
          for (int r = 0; r < 4; ++r) {
            const int key = kb + kt * 16 + l4 * 4 + r;
            const int qi = qw + qt * 16 + l15;
            z[kt][qt][r] = (key <= qi) ? z[kt][qt][r] : -3e38f;
          }
    }

    // lane-local online softmax per q-subtile (32 scores each)
#pragma unroll
    for (int qt = 0; qt < 2; ++qt) {
      float tm[16];
#pragma unroll
      for (int i = 0; i < 16; ++i)
        tm[i] = fmaxf(z[(2 * i) >> 2][qt][(2 * i) & 3], z[(2 * i + 1) >> 2][qt][(2 * i + 1) & 3]);
#pragma unroll
      for (int i = 0; i < 8; ++i) tm[i] = fmaxf(tm[i], tm[i + 8]);
#pragma unroll
      for (int i = 0; i < 4; ++i) tm[i] = fmaxf(tm[i], tm[i + 4]);
      float pm = fmaxf(fmaxf(tm[0], tm[2]), fmaxf(tm[1], tm[3]));
      pm = fmaxf(pm, __shfl_xor(pm, 16, 64));
      pm = fmaxf(pm, __shfl_xor(pm, 32, 64));

      if (!__all(pm <= m_[qt] + 11.5f)) {  // defer-max (log2 domain)
        const float mn = fmaxf(m_[qt], pm);
        const float sf = exp2f(m_[qt] - mn);
        m_[qt] = mn;
        l_[qt] *= sf;
#pragma unroll
        for (int dt = 0; dt < 4; ++dt)
#pragma unroll
          for (int r = 0; r < 4; ++r) accO[dt][qt][r] *= sf;
      }

#pragma unroll
      for (int kt = 0; kt < 8; ++kt)
#pragma unroll
        for (int r = 0; r < 4; ++r)
          z[kt][qt][r] = exp2f(z[kt][qt][r] - m_[qt]);
      float ts[16];
#pragma unroll
      for (int i = 0; i < 16; ++i)
        ts[i] = z[(2 * i) >> 2][qt][(2 * i) & 3] + z[(2 * i + 1) >> 2][qt][(2 * i + 1) & 3];
#pragma unroll
      for (int i = 0; i < 8; ++i) ts[i] += ts[i + 8];
#pragma unroll
      for (int i = 0; i < 4; ++i) ts[i] += ts[i + 4];
      float rs = (ts[0] + ts[2]) + (ts[1] + ts[3]);
      rs += __shfl_xor(rs, 16, 64);
      rs += __shfl_xor(rs, 32, 64);
      l_[qt] += rs;
    }

    // PV in two 64-key halves, reusing one 4KB/wave P buffer
#pragma unroll
    for (int h = 0; h < 2; ++h) {
#pragma unroll
      for (int qt = 0; qt < 2; ++qt) {
        const int q = qt * 16 + l15;
#pragma unroll
        for (int k4 = 0; k4 < 4; ++k4) {
          const int kt = h * 4 + k4;
          bf16x4 pk;
#pragma unroll
          for (int r = 0; r < 4; ++r) pk[r] = (__bf16)z[kt][qt][r];
          const int c16 = k4 * 2 + (l4 >> 1);
          *reinterpret_cast<bf16x4*>(pwb + q * 128 + ((c16 ^ (q & 7)) << 4) + (l4 & 1) * 8) = pk;
        }
      }
      asm volatile("s_waitcnt lgkmcnt(0)" ::: "memory");
      __builtin_amdgcn_sched_barrier(0);

      __builtin_amdgcn_s_setprio(1);
#pragma unroll
      for (int ks2 = 0; ks2 < 2; ++ks2) {
        bf16x8 pb[2];
#pragma unroll
        for (int qt = 0; qt < 2; ++qt) {
          const int q = qt * 16 + l15;
          pb[qt] = *reinterpret_cast<const bf16x8*>(pwb + q * 128 + ((((ks2 << 2) + l4) ^ (q & 7)) << 4));
        }
#pragma unroll
        for (int dt = 0; dt < 4; ++dt) {
          const int row = dt * 16 + l15;
          bf16x8 vf = *reinterpret_cast<const bf16x8*>(
              vsb + row * 256 + ((((h * 2 + ks2) * 4 + l4) ^ l15) << 4));
#pragma unroll
          for (int qt = 0; qt < 2; ++qt)
            accO[dt][qt] = __builtin_amdgcn_mfma_f32_16x16x32_bf16(vf, pb[qt], accO[dt][qt], 0, 0, 0);
        }
      }
      __builtin_amdgcn_s_setprio(0);
      __builtin_amdgcn_sched_barrier(0);  // keep next half's P writes below these reads
    }
    cur ^= 1;
  }

  const int b = bh >> 4, h = bh & 15;
#pragma unroll
  for (int qt = 0; qt < 2; ++qt) {
    const float inv = 1.0f / l_[qt];
    const int q = qw + qt * 16 + l15;
#pragma unroll
    for (int dt = 0; dt < 4; ++dt) {
      bf16x4 o;
#pragma unroll
      for (int r = 0; r < 4; ++r) o[r] = (__bf16)(accO[dt][qt][r] * inv);
      *reinterpret_cast<bf16x4*>(&Y[((size_t)(b * TT + q)) * NE + h * 64 + dt * 16 + l4 * 4]) = o;
    }
  }
}

extern "C" void kernel_launch(void* const* d_in, const int* in_sizes, int n_in,
                              void* d_out, int out_size, void* d_ws, size_t ws_size,
                              hipStream_t stream) {
  const float* x  = (const float*)d_in[0];
  const float* Wq = (const float*)d_in[1];
  const float* bq = (const float*)d_in[2];
  const float* Wk = (const float*)d_in[3];
  const float* bk = (const float*)d_in[4];
  const float* Wv = (const float*)d_in[5];
  const float* bv = (const float*)d_in[6];
  const float* Wp = (const float*)d_in[7];
  const float* bp = (const float*)d_in[8];

  char* ws = (char*)d_ws;
  const size_t MB = 1u << 20;
  unsigned short* xb   = (unsigned short*)(ws + 0 * MB);   // 8 MB  [4096][1024]
  unsigned short* Wqkv = (unsigned short*)(ws + 8 * MB);   // 6 MB  [3072][1024] (q,k,v)
  unsigned short* Wpb  = (unsigned short*)(ws + 14 * MB);  // 2 MB  [1024][1024]
  unsigned short* Qb   = (unsigned short*)(ws + 16 * MB);  // 8 MB  [B,H,T,64]
  unsigned short* Kb   = (unsigned short*)(ws + 24 * MB);  // 8 MB  [B,H,T,64]
  unsigned short* Vtb  = (unsigned short*)(ws + 32 * MB);  // 8 MB  [B,H,64,T]
  unsigned short* yb   = (unsigned short*)(ws + 40 * MB);  // 8 MB  [B,T,NE]

  cvt_bf16<<<MM * NE / 4 / 256, 256, 0, stream>>>(x, xb, MM * NE / 4);
  cvt_w<<<4 * NE * NE / 4 / 256, 256, 0, stream>>>(Wq, Wk, Wv, Wp, Wqkv);

  // fused QKV: M=4096, N=3072 -> 24 x 32 = 768 blocks (3/CU)
  gemm_nt<128, 1><<<768, 256, 0, stream>>>(xb, Wqkv, bq, bk, bv, Qb, Kb, Vtb, NE, 24);

  attn<<<512, 256, 0, stream>>>(Qb, Kb, Vtb, yb);

  // proj: BM=64 -> 8 x 64 = 512 blocks (2/CU)
  gemm_nt<64, 0><<<512, 256, 0, stream>>>(yb, Wpb, bp, nullptr, nullptr, d_out, nullptr, nullptr, NE, 8);
}